// Round 1
// baseline (393.536 us; speedup 1.0000x reference)
//
#include <hip/hip_runtime.h>
#include <hip/hip_fp16.h>
#include <math.h>

// Problem dims
#define NN   8192   // nodes / rows
#define KD   8192   // K of big GEMMs
#define HID  200
#define NP   224    // HID padded to 14*16
#define OUTC 5

// GEMM tiling
#define BM   128
#define BK   32
#define KS   4      // K-split chunks
#define KCH  (KD / KS)
#define LPAD 40     // halves per LDS row (32 + 8 pad); 80B stride = 5*16B -> aligned, 2-way free

typedef _Float16 f16;
typedef __attribute__((ext_vector_type(4))) _Float16 f16x4;
typedef __attribute__((ext_vector_type(8))) _Float16 f16x8;
typedef __attribute__((ext_vector_type(4))) float f32x4;

// -------- split helper: v = h + l * 2^-11, h/l fp16 ----------
__device__ __forceinline__ void split2(float v, f16& h, f16& l) {
    h = (f16)v;
    l = (f16)((v - (float)h) * 2048.0f);
}

// ============ 1. W1 [8192][200] fp32 -> W1hT/W1lT [224][8192] fp16 (zero-padded) ============
__global__ __launch_bounds__(256) void k_prep_w1(const float* __restrict__ W1,
                                                 f16* __restrict__ BhT, f16* __restrict__ BlT) {
    __shared__ float tile[64][65];
    const int k0 = blockIdx.x * 64;
    const int n0 = blockIdx.y * 64;
    const int t = threadIdx.x;
    #pragma unroll
    for (int p = 0; p < 16; ++p) {
        int idx = t + p * 256;              // 0..4095
        int kk = idx >> 6, nn = idx & 63;
        int n = n0 + nn;
        float v = (n < HID) ? W1[(size_t)(k0 + kk) * HID + n] : 0.0f;
        tile[kk][nn] = v;
    }
    __syncthreads();
    #pragma unroll
    for (int p = 0; p < 16; ++p) {
        int idx = t + p * 256;
        int nn = idx >> 6, kk = idx & 63;
        int n = n0 + nn;
        if (n < NP) {
            f16 h, l; split2(tile[kk][nn], h, l);
            BhT[(size_t)n * KD + k0 + kk] = h;
            BlT[(size_t)n * KD + k0 + kk] = l;
        }
    }
}

// ============ 2. main GEMM: CP[ky] = A[:, kchunk] @ B[kchunk, :]  (fp16 split-2, 3 products) ====
// A fp32 [8192][8192], B pre-split fp16ᵀ [224][8192]. Grid (64, KS), 512 thr (8 waves 4x2).
__global__ __launch_bounds__(512, 2) void k_gemm(const float* __restrict__ A,
                                                 const f16* __restrict__ BhT,
                                                 const f16* __restrict__ BlT,
                                                 float* __restrict__ CP) {
    __shared__ __align__(16) f16 Ah[BM * LPAD];
    __shared__ __align__(16) f16 Al[BM * LPAD];
    __shared__ __align__(16) f16 Bh[NP * LPAD];
    __shared__ __align__(16) f16 Bl[NP * LPAD];

    const int t = threadIdx.x;
    const int lane = t & 63;
    const int wave = t >> 6;
    const int wm = wave >> 1, wn = wave & 1;   // 4 wave-rows x 2 wave-cols
    const int l15 = lane & 15, g = lane >> 4;  // MFMA frag coords
    const int m0 = blockIdx.x * BM;
    const size_t kc0 = (size_t)blockIdx.y * KCH;

    f32x4 acc_hi[2][7], acc_lo[2][7];
    #pragma unroll
    for (int m = 0; m < 2; ++m)
        #pragma unroll
        for (int n = 0; n < 7; ++n) {
            acc_hi[m][n] = (f32x4){0.f, 0.f, 0.f, 0.f};
            acc_lo[m][n] = (f32x4){0.f, 0.f, 0.f, 0.f};
        }

    for (int ks = 0; ks < KCH; ks += BK) {
        const size_t kb = kc0 + ks;
        __syncthreads();
        // ---- stage A tile [128][32] fp32 -> split fp16 hi/lo in LDS ----
        #pragma unroll
        for (int p = 0; p < 2; ++p) {
            int f = t + p * 512;                 // 0..1023 float4s
            int row = f >> 3, q = f & 7;
            float4 v = *(const float4*)(A + (size_t)(m0 + row) * KD + kb + (size_t)q * 4);
            f16x4 hv, lv;
            { f16 h, l; split2(v.x, h, l); hv[0] = h; lv[0] = l; }
            { f16 h, l; split2(v.y, h, l); hv[1] = h; lv[1] = l; }
            { f16 h, l; split2(v.z, h, l); hv[2] = h; lv[2] = l; }
            { f16 h, l; split2(v.w, h, l); hv[3] = h; lv[3] = l; }
            *(f16x4*)&Ah[row * LPAD + q * 4] = hv;
            *(f16x4*)&Al[row * LPAD + q * 4] = lv;
        }
        // ---- stage B tile [224][32] fp16 (pre-split) ----
        #pragma unroll
        for (int p = 0; p < 2; ++p) {
            int u = t + p * 512;                 // 896 f16x8 units per array
            if (u < 896) {
                int row = u >> 2, q = u & 3;
                *(f16x8*)&Bh[row * LPAD + q * 8] = *(const f16x8*)(BhT + (size_t)row * KD + kb + (size_t)q * 8);
                *(f16x8*)&Bl[row * LPAD + q * 8] = *(const f16x8*)(BlT + (size_t)row * KD + kb + (size_t)q * 8);
            }
        }
        __syncthreads();
        // ---- compute: 3 products (AhBh; AhBl + AlBh scaled 2^11) ----
        f16x8 a_h[2], a_l[2];
        #pragma unroll
        for (int m = 0; m < 2; ++m) {
            int r = wm * 32 + m * 16 + l15;
            a_h[m] = *(const f16x8*)&Ah[r * LPAD + g * 8];
            a_l[m] = *(const f16x8*)&Al[r * LPAD + g * 8];
        }
        #pragma unroll
        for (int n = 0; n < 7; ++n) {
            int c = wn * 112 + n * 16 + l15;
            f16x8 b_h = *(const f16x8*)&Bh[c * LPAD + g * 8];
            f16x8 b_l = *(const f16x8*)&Bl[c * LPAD + g * 8];
            #pragma unroll
            for (int m = 0; m < 2; ++m) {
                acc_hi[m][n] = __builtin_amdgcn_mfma_f32_16x16x32_f16(a_h[m], b_h, acc_hi[m][n], 0, 0, 0);
                acc_lo[m][n] = __builtin_amdgcn_mfma_f32_16x16x32_f16(a_h[m], b_l, acc_lo[m][n], 0, 0, 0);
                acc_lo[m][n] = __builtin_amdgcn_mfma_f32_16x16x32_f16(a_l[m], b_h, acc_lo[m][n], 0, 0, 0);
            }
        }
    }
    // ---- epilogue: partial C (fp32) ----
    float* o = CP + (size_t)blockIdx.y * ((size_t)NN * NP);
    #pragma unroll
    for (int m = 0; m < 2; ++m) {
        #pragma unroll
        for (int n = 0; n < 7; ++n) {
            int rb = m0 + wm * 32 + m * 16 + g * 4;
            int c = wn * 112 + n * 16 + l15;
            #pragma unroll
            for (int r = 0; r < 4; ++r)
                o[(size_t)(rb + r) * NP + c] = acc_hi[m][n][r] + acc_lo[m][n][r] * (1.0f / 2048.0f);
        }
    }
}

// ============ 3. combine K-split partials -> split fp16, TRANSPOSED (feeds GEMM2's B) ============
__global__ __launch_bounds__(256) void k_combine_split(const float* __restrict__ CP,
                                                       f16* __restrict__ ShT, f16* __restrict__ SlT) {
    __shared__ float tile[64][65];
    const size_t SZ = (size_t)NN * NP;
    const int m0 = blockIdx.x * 64;
    const int n0 = blockIdx.y * 64;
    const int t = threadIdx.x;
    #pragma unroll
    for (int p = 0; p < 16; ++p) {
        int idx = t + p * 256;
        int mm = idx >> 6, nn = idx & 63;
        int n = n0 + nn;
        float s = 0.0f;
        if (n < NP) {
            size_t off = (size_t)(m0 + mm) * NP + n;
            s = CP[off] + CP[off + SZ] + CP[off + 2 * SZ] + CP[off + 3 * SZ];
        }
        tile[mm][nn] = s;
    }
    __syncthreads();
    #pragma unroll
    for (int p = 0; p < 16; ++p) {
        int idx = t + p * 256;
        int nn = idx >> 6, mm = idx & 63;
        int n = n0 + nn;
        if (n < NP) {
            f16 h, l; split2(tile[mm][nn], h, l);
            ShT[(size_t)n * KD + m0 + mm] = h;
            SlT[(size_t)n * KD + m0 + mm] = l;
        }
    }
}

// ============ 4. combine + bias + relu -> H fp32 [8192][224] ============
__global__ __launch_bounds__(256) void k_combine_bias_relu(const float* __restrict__ CP,
                                                           const float* __restrict__ b1,
                                                           float* __restrict__ H) {
    const size_t SZ = (size_t)NN * NP;
    const int row = blockIdx.x;
    const int t = threadIdx.x;
    if (t < NP) {
        size_t off = (size_t)row * NP + t;
        float s = CP[off] + CP[off + SZ] + CP[off + 2 * SZ] + CP[off + 3 * SZ];
        s += (t < HID) ? b1[t] : 0.0f;
        H[off] = fmaxf(s, 0.0f);
    }
}

// ============ 5. S2ᵀ[5][8192] = (H @ W2)ᵀ — one wave per row ============
__global__ __launch_bounds__(256) void k_hw2(const float* __restrict__ H,
                                             const float* __restrict__ W2,
                                             float* __restrict__ S2T) {
    const int t = threadIdx.x;
    const int wave = t >> 6, lane = t & 63;
    const int row = blockIdx.x * 4 + wave;
    float acc[OUTC] = {0.f, 0.f, 0.f, 0.f, 0.f};
    for (int j = lane; j < HID; j += 64) {
        float h = H[(size_t)row * NP + j];
        #pragma unroll
        for (int c = 0; c < OUTC; ++c) acc[c] += h * W2[j * OUTC + c];
    }
    #pragma unroll
    for (int c = 0; c < OUTC; ++c)
        #pragma unroll
        for (int off = 32; off; off >>= 1) acc[c] += __shfl_down(acc[c], off, 64);
    if (lane == 0) {
        #pragma unroll
        for (int c = 0; c < OUTC; ++c) S2T[(size_t)c * NN + row] = acc[c];
    }
}

// ============ 6. logits = adj @ S2 + b2 ; softmax -> out. 8 rows per block. ============
__global__ __launch_bounds__(256) void k_final(const float* __restrict__ adj,
                                               const float* __restrict__ S2T,
                                               const float* __restrict__ b2,
                                               float* __restrict__ out) {
    __shared__ float red[4][8][OUTC];
    const int t = threadIdx.x, wave = t >> 6, lane = t & 63;
    const int row0 = blockIdx.x * 8;
    float acc[8][OUTC];
    #pragma unroll
    for (int r = 0; r < 8; ++r)
        #pragma unroll
        for (int c = 0; c < OUTC; ++c) acc[r][c] = 0.f;

    for (int jj = 0; jj < 8; ++jj) {
        int kb = (t + jj * 256) * 4;
        float4 s2[OUTC];
        #pragma unroll
        for (int c = 0; c < OUTC; ++c) s2[c] = *(const float4*)(S2T + (size_t)c * NN + kb);
        #pragma unroll
        for (int r = 0; r < 8; ++r) {
            float4 a = *(const float4*)(adj + (size_t)(row0 + r) * KD + kb);
            #pragma unroll
            for (int c = 0; c < OUTC; ++c)
                acc[r][c] += a.x * s2[c].x + a.y * s2[c].y + a.z * s2[c].z + a.w * s2[c].w;
        }
    }
    #pragma unroll
    for (int r = 0; r < 8; ++r)
        #pragma unroll
        for (int c = 0; c < OUTC; ++c) {
            float v = acc[r][c];
            #pragma unroll
            for (int off = 32; off; off >>= 1) v += __shfl_down(v, off, 64);
            if (lane == 0) red[wave][r][c] = v;
        }
    __syncthreads();
    if (t < 8) {
        int r = t;
        float lg[OUTC];
        #pragma unroll
        for (int c = 0; c < OUTC; ++c)
            lg[c] = red[0][r][c] + red[1][r][c] + red[2][r][c] + red[3][r][c] + b2[c];
        float mx = lg[0];
        #pragma unroll
        for (int c = 1; c < OUTC; ++c) mx = fmaxf(mx, lg[c]);
        float e[OUTC], s = 0.f;
        #pragma unroll
        for (int c = 0; c < OUTC; ++c) { e[c] = expf(lg[c] - mx); s += e[c]; }
        float inv = 1.0f / s;
        #pragma unroll
        for (int c = 0; c < OUTC; ++c) out[(size_t)(row0 + r) * OUTC + c] = e[c] * inv;
    }
}

// ===================== launcher =====================
extern "C" void kernel_launch(void* const* d_in, const int* in_sizes, int n_in,
                              void* d_out, int out_size, void* d_ws, size_t ws_size,
                              hipStream_t stream) {
    const float* x   = (const float*)d_in[0];
    const float* adj = (const float*)d_in[1];
    const float* W1  = (const float*)d_in[2];
    const float* b1  = (const float*)d_in[3];
    const float* W2  = (const float*)d_in[4];
    const float* b2  = (const float*)d_in[5];
    float* out = (float*)d_out;

    char* ws = (char*)d_ws;
    const size_t SPLIT_BYTES = (size_t)NP * KD * sizeof(f16);   // 3,670,016
    f16*   W1hT = (f16*)(ws);
    f16*   W1lT = (f16*)(ws + SPLIT_BYTES);
    f16*   S1hT = (f16*)(ws + 2 * SPLIT_BYTES);
    f16*   S1lT = (f16*)(ws + 3 * SPLIT_BYTES);
    float* H    = (float*)(ws + 4 * SPLIT_BYTES);
    float* S2T  = (float*)(ws + 4 * SPLIT_BYTES + (size_t)NN * NP * sizeof(float));
    float* CP   = (float*)(ws + 4 * SPLIT_BYTES + (size_t)NN * NP * sizeof(float)
                              + (size_t)OUTC * NN * sizeof(float));

    // 1. W1 -> padded, transposed, fp16-split
    k_prep_w1<<<dim3(KD / 64, (NP + 63) / 64), 256, 0, stream>>>(W1, W1hT, W1lT);
    // 2. S1 = x @ W1 (K-split partials)
    k_gemm<<<dim3(NN / BM, KS), 512, 0, stream>>>(x, W1hT, W1lT, CP);
    // 3. reduce partials -> S1ᵀ fp16-split
    k_combine_split<<<dim3(NN / 64, (NP + 63) / 64), 256, 0, stream>>>(CP, S1hT, S1lT);
    // 4. adj @ S1 (K-split partials)
    k_gemm<<<dim3(NN / BM, KS), 512, 0, stream>>>(adj, S1hT, S1lT, CP);
    // 5. H = relu(. + b1)
    k_combine_bias_relu<<<NN, 256, 0, stream>>>(CP, b1, H);
    // 6. S2ᵀ = (H @ W2)ᵀ
    k_hw2<<<NN / 4, 256, 0, stream>>>(H, W2, S2T);
    // 7. softmax(adj @ S2 + b2)
    k_final<<<NN / 8, 256, 0, stream>>>(adj, S2T, b2, out);
}

// Round 2
// 337.115 us; speedup vs baseline: 1.1674x; 1.1674x over previous
//
#include <hip/hip_runtime.h>
#include <hip/hip_fp16.h>
#include <math.h>

// Problem dims
#define NN   8192   // nodes / rows
#define KD   8192   // K of big GEMMs
#define HID  200
#define NP   224    // HID padded to 14*16
#define OUTC 5

// GEMM tiling
#define BM   128
#define BK   32
#define KS   4      // K-split chunks
#define KCH  (KD / KS)
#define NT   (KCH / BK)   // K-steps per block = 64
#define LPAD 40     // halves per LDS row (32 + 8 pad); 80B stride = 5*16B -> aligned b128

typedef _Float16 f16;
typedef __attribute__((ext_vector_type(4))) _Float16 f16x4;
typedef __attribute__((ext_vector_type(8))) _Float16 f16x8;
typedef __attribute__((ext_vector_type(4))) float f32x4;

// -------- split helper: v = h + l * 2^-11, h/l fp16 ----------
__device__ __forceinline__ void split2(float v, f16& h, f16& l) {
    h = (f16)v;
    l = (f16)((v - (float)h) * 2048.0f);
}

// ============ 1. W1 [8192][200] fp32 -> W1hT/W1lT [224][8192] fp16 (zero-padded) ============
__global__ __launch_bounds__(256) void k_prep_w1(const float* __restrict__ W1,
                                                 f16* __restrict__ BhT, f16* __restrict__ BlT) {
    __shared__ float tile[64][65];
    const int k0 = blockIdx.x * 64;
    const int n0 = blockIdx.y * 64;
    const int t = threadIdx.x;
    #pragma unroll
    for (int p = 0; p < 16; ++p) {
        int idx = t + p * 256;              // 0..4095
        int kk = idx >> 6, nn = idx & 63;
        int n = n0 + nn;
        float v = (n < HID) ? W1[(size_t)(k0 + kk) * HID + n] : 0.0f;
        tile[kk][nn] = v;
    }
    __syncthreads();
    #pragma unroll
    for (int p = 0; p < 16; ++p) {
        int idx = t + p * 256;
        int nn = idx >> 6, kk = idx & 63;
        int n = n0 + nn;
        if (n < NP) {
            f16 h, l; split2(tile[kk][nn], h, l);
            BhT[(size_t)n * KD + k0 + kk] = h;
            BlT[(size_t)n * KD + k0 + kk] = l;
        }
    }
}

// ============ 2. main GEMM: CP[ky] = A[:, kchunk] @ B[kchunk, :]  (fp16 split-2, 3 products) ====
// A fp32 [8192][8192], B pre-split fp16ᵀ [224][8192]. Grid (64, KS), 512 thr (8 waves 4x2).
// Register-prefetch pipeline: global loads for tile i+1 issued before MFMA phase of tile i.
__global__ __launch_bounds__(512, 2) void k_gemm(const float* __restrict__ A,
                                                 const f16* __restrict__ BhT,
                                                 const f16* __restrict__ BlT,
                                                 float* __restrict__ CP) {
    __shared__ __align__(16) f16 Ah[BM * LPAD];
    __shared__ __align__(16) f16 Al[BM * LPAD];
    __shared__ __align__(16) f16 Bh[NP * LPAD];
    __shared__ __align__(16) f16 Bl[NP * LPAD];

    const int t = threadIdx.x;
    const int lane = t & 63;
    const int wave = t >> 6;
    const int wm = wave >> 1, wn = wave & 1;   // 4 wave-rows x 2 wave-cols
    const int l15 = lane & 15, g = lane >> 4;  // MFMA frag coords
    const int m0 = blockIdx.x * BM;
    const size_t kc0 = (size_t)blockIdx.y * KCH;

    // staging mapping: A -> thread owns one 8-float chunk (row arow, chunk aq)
    const int arow = t >> 2, aq = t & 3;
    // B -> unit u = row*4 + q (f16x8 chunks); u0 = t always, u1 = t+512 when t<384
    const int br0 = t >> 2, bq0 = t & 3;
    const int u1 = t + 512;
    const int br1 = u1 >> 2, bq1 = u1 & 3;
    const bool hasB1 = (t < 384);

    const float* Aptr = A + (size_t)(m0 + arow) * KD + kc0 + (size_t)aq * 8;
    const f16* Bh0p = BhT + (size_t)br0 * KD + kc0 + (size_t)bq0 * 8;
    const f16* Bl0p = BlT + (size_t)br0 * KD + kc0 + (size_t)bq0 * 8;
    const f16* Bh1p = BhT + (size_t)br1 * KD + kc0 + (size_t)bq1 * 8;
    const f16* Bl1p = BlT + (size_t)br1 * KD + kc0 + (size_t)bq1 * 8;

    f32x4 acc_hi[2][7], acc_lo[2][7];
    #pragma unroll
    for (int m = 0; m < 2; ++m)
        #pragma unroll
        for (int n = 0; n < 7; ++n) {
            acc_hi[m][n] = (f32x4){0.f, 0.f, 0.f, 0.f};
            acc_lo[m][n] = (f32x4){0.f, 0.f, 0.f, 0.f};
        }

    // staged registers (tile in flight)
    float4 v0, v1;
    f16x8 gbh0, gbl0, gbh1, gbl1;

    auto LOAD = [&](int ks) {
        v0 = *(const float4*)(Aptr + ks);
        v1 = *(const float4*)(Aptr + ks + 4);
        gbh0 = *(const f16x8*)(Bh0p + ks);
        gbl0 = *(const f16x8*)(Bl0p + ks);
        if (hasB1) {
            gbh1 = *(const f16x8*)(Bh1p + ks);
            gbl1 = *(const f16x8*)(Bl1p + ks);
        }
    };
    auto STORE = [&]() {
        f16x8 hv, lv;
        float vv[8] = {v0.x, v0.y, v0.z, v0.w, v1.x, v1.y, v1.z, v1.w};
        #pragma unroll
        for (int j = 0; j < 8; ++j) { f16 h, l; split2(vv[j], h, l); hv[j] = h; lv[j] = l; }
        *(f16x8*)&Ah[arow * LPAD + aq * 8] = hv;
        *(f16x8*)&Al[arow * LPAD + aq * 8] = lv;
        *(f16x8*)&Bh[br0 * LPAD + bq0 * 8] = gbh0;
        *(f16x8*)&Bl[br0 * LPAD + bq0 * 8] = gbl0;
        if (hasB1) {
            *(f16x8*)&Bh[br1 * LPAD + bq1 * 8] = gbh1;
            *(f16x8*)&Bl[br1 * LPAD + bq1 * 8] = gbl1;
        }
    };

    LOAD(0);
    for (int i = 0; i < NT; ++i) {
        __syncthreads();                    // prev compute's LDS reads done
        STORE();                            // tile i regs -> LDS (vmcnt wait here)
        __syncthreads();                    // writes visible
        if (i + 1 < NT) LOAD((i + 1) * BK); // issue next tile loads (in flight over MFMA)

        f16x8 a_h[2], a_l[2];
        #pragma unroll
        for (int m = 0; m < 2; ++m) {
            int r = wm * 32 + m * 16 + l15;
            a_h[m] = *(const f16x8*)&Ah[r * LPAD + g * 8];
            a_l[m] = *(const f16x8*)&Al[r * LPAD + g * 8];
        }
        __builtin_amdgcn_s_setprio(1);
        #pragma unroll
        for (int n = 0; n < 7; ++n) {
            int c = wn * 112 + n * 16 + l15;
            f16x8 b_h = *(const f16x8*)&Bh[c * LPAD + g * 8];
            f16x8 b_l = *(const f16x8*)&Bl[c * LPAD + g * 8];
            #pragma unroll
            for (int m = 0; m < 2; ++m) {
                acc_hi[m][n] = __builtin_amdgcn_mfma_f32_16x16x32_f16(a_h[m], b_h, acc_hi[m][n], 0, 0, 0);
                acc_lo[m][n] = __builtin_amdgcn_mfma_f32_16x16x32_f16(a_h[m], b_l, acc_lo[m][n], 0, 0, 0);
                acc_lo[m][n] = __builtin_amdgcn_mfma_f32_16x16x32_f16(a_l[m], b_h, acc_lo[m][n], 0, 0, 0);
            }
        }
        __builtin_amdgcn_s_setprio(0);
    }

    // ---- epilogue: partial C (fp32) ----
    float* o = CP + (size_t)blockIdx.y * ((size_t)NN * NP);
    #pragma unroll
    for (int m = 0; m < 2; ++m) {
        #pragma unroll
        for (int n = 0; n < 7; ++n) {
            int rb = m0 + wm * 32 + m * 16 + g * 4;
            int c = wn * 112 + n * 16 + l15;
            #pragma unroll
            for (int r = 0; r < 4; ++r)
                o[(size_t)(rb + r) * NP + c] = acc_hi[m][n][r] + acc_lo[m][n][r] * (1.0f / 2048.0f);
        }
    }
}

// ============ 3. combine K-split partials -> split fp16, TRANSPOSED (feeds GEMM2's B) ============
__global__ __launch_bounds__(256) void k_combine_split(const float* __restrict__ CP,
                                                       f16* __restrict__ ShT, f16* __restrict__ SlT) {
    __shared__ float tile[64][65];
    const size_t SZ = (size_t)NN * NP;
    const int m0 = blockIdx.x * 64;
    const int n0 = blockIdx.y * 64;
    const int t = threadIdx.x;
    #pragma unroll
    for (int p = 0; p < 16; ++p) {
        int idx = t + p * 256;
        int mm = idx >> 6, nn = idx & 63;
        int n = n0 + nn;
        float s = 0.0f;
        if (n < NP) {
            size_t off = (size_t)(m0 + mm) * NP + n;
            s = CP[off] + CP[off + SZ] + CP[off + 2 * SZ] + CP[off + 3 * SZ];
        }
        tile[mm][nn] = s;
    }
    __syncthreads();
    #pragma unroll
    for (int p = 0; p < 16; ++p) {
        int idx = t + p * 256;
        int nn = idx >> 6, mm = idx & 63;
        int n = n0 + nn;
        if (n < NP) {
            f16 h, l; split2(tile[mm][nn], h, l);
            ShT[(size_t)n * KD + m0 + mm] = h;
            SlT[(size_t)n * KD + m0 + mm] = l;
        }
    }
}

// ============ 4. combine + bias + relu -> H fp32 [8192][224] ============
__global__ __launch_bounds__(256) void k_combine_bias_relu(const float* __restrict__ CP,
                                                           const float* __restrict__ b1,
                                                           float* __restrict__ H) {
    const size_t SZ = (size_t)NN * NP;
    const int row = blockIdx.x;
    const int t = threadIdx.x;
    if (t < NP) {
        size_t off = (size_t)row * NP + t;
        float s = CP[off] + CP[off + SZ] + CP[off + 2 * SZ] + CP[off + 3 * SZ];
        s += (t < HID) ? b1[t] : 0.0f;
        H[off] = fmaxf(s, 0.0f);
    }
}

// ============ 5. S2ᵀ[5][8192] = (H @ W2)ᵀ — one wave per row ============
__global__ __launch_bounds__(256) void k_hw2(const float* __restrict__ H,
                                             const float* __restrict__ W2,
                                             float* __restrict__ S2T) {
    const int t = threadIdx.x;
    const int wave = t >> 6, lane = t & 63;
    const int row = blockIdx.x * 4 + wave;
    float acc[OUTC] = {0.f, 0.f, 0.f, 0.f, 0.f};
    for (int j = lane; j < HID; j += 64) {
        float h = H[(size_t)row * NP + j];
        #pragma unroll
        for (int c = 0; c < OUTC; ++c) acc[c] += h * W2[j * OUTC + c];
    }
    #pragma unroll
    for (int c = 0; c < OUTC; ++c)
        #pragma unroll
        for (int off = 32; off; off >>= 1) acc[c] += __shfl_down(acc[c], off, 64);
    if (lane == 0) {
        #pragma unroll
        for (int c = 0; c < OUTC; ++c) S2T[(size_t)c * NN + row] = acc[c];
    }
}

// ============ 6. logits = adj @ S2 + b2 ; softmax -> out. 8 rows per block. ============
__global__ __launch_bounds__(256) void k_final(const float* __restrict__ adj,
                                               const float* __restrict__ S2T,
                                               const float* __restrict__ b2,
                                               float* __restrict__ out) {
    __shared__ float red[4][8][OUTC];
    const int t = threadIdx.x, wave = t >> 6, lane = t & 63;
    const int row0 = blockIdx.x * 8;
    float acc[8][OUTC];
    #pragma unroll
    for (int r = 0; r < 8; ++r)
        #pragma unroll
        for (int c = 0; c < OUTC; ++c) acc[r][c] = 0.f;

    for (int jj = 0; jj < 8; ++jj) {
        int kb = (t + jj * 256) * 4;
        float4 s2[OUTC];
        #pragma unroll
        for (int c = 0; c < OUTC; ++c) s2[c] = *(const float4*)(S2T + (size_t)c * NN + kb);
        #pragma unroll
        for (int r = 0; r < 8; ++r) {
            float4 a = *(const float4*)(adj + (size_t)(row0 + r) * KD + kb);
            #pragma unroll
            for (int c = 0; c < OUTC; ++c)
                acc[r][c] += a.x * s2[c].x + a.y * s2[c].y + a.z * s2[c].z + a.w * s2[c].w;
        }
    }
    #pragma unroll
    for (int r = 0; r < 8; ++r)
        #pragma unroll
        for (int c = 0; c < OUTC; ++c) {
            float v = acc[r][c];
            #pragma unroll
            for (int off = 32; off; off >>= 1) v += __shfl_down(v, off, 64);
            if (lane == 0) red[wave][r][c] = v;
        }
    __syncthreads();
    if (t < 8) {
        int r = t;
        float lg[OUTC];
        #pragma unroll
        for (int c = 0; c < OUTC; ++c)
            lg[c] = red[0][r][c] + red[1][r][c] + red[2][r][c] + red[3][r][c] + b2[c];
        float mx = lg[0];
        #pragma unroll
        for (int c = 1; c < OUTC; ++c) mx = fmaxf(mx, lg[c]);
        float e[OUTC], s = 0.f;
        #pragma unroll
        for (int c = 0; c < OUTC; ++c) { e[c] = expf(lg[c] - mx); s += e[c]; }
        float inv = 1.0f / s;
        #pragma unroll
        for (int c = 0; c < OUTC; ++c) out[(size_t)(row0 + r) * OUTC + c] = e[c] * inv;
    }
}

// ===================== launcher =====================
extern "C" void kernel_launch(void* const* d_in, const int* in_sizes, int n_in,
                              void* d_out, int out_size, void* d_ws, size_t ws_size,
                              hipStream_t stream) {
    const float* x   = (const float*)d_in[0];
    const float* adj = (const float*)d_in[1];
    const float* W1  = (const float*)d_in[2];
    const float* b1  = (const float*)d_in[3];
    const float* W2  = (const float*)d_in[4];
    const float* b2  = (const float*)d_in[5];
    float* out = (float*)d_out;

    char* ws = (char*)d_ws;
    const size_t SPLIT_BYTES = (size_t)NP * KD * sizeof(f16);   // 3,670,016
    f16*   W1hT = (f16*)(ws);
    f16*   W1lT = (f16*)(ws + SPLIT_BYTES);
    f16*   S1hT = (f16*)(ws + 2 * SPLIT_BYTES);
    f16*   S1lT = (f16*)(ws + 3 * SPLIT_BYTES);
    float* H    = (float*)(ws + 4 * SPLIT_BYTES);
    float* S2T  = (float*)(ws + 4 * SPLIT_BYTES + (size_t)NN * NP * sizeof(float));
    float* CP   = (float*)(ws + 4 * SPLIT_BYTES + (size_t)NN * NP * sizeof(float)
                              + (size_t)OUTC * NN * sizeof(float));

    // 1. W1 -> padded, transposed, fp16-split
    k_prep_w1<<<dim3(KD / 64, (NP + 63) / 64), 256, 0, stream>>>(W1, W1hT, W1lT);
    // 2. S1 = x @ W1 (K-split partials)
    k_gemm<<<dim3(NN / BM, KS), 512, 0, stream>>>(x, W1hT, W1lT, CP);
    // 3. reduce partials -> S1ᵀ fp16-split
    k_combine_split<<<dim3(NN / 64, (NP + 63) / 64), 256, 0, stream>>>(CP, S1hT, S1lT);
    // 4. adj @ S1 (K-split partials)
    k_gemm<<<dim3(NN / BM, KS), 512, 0, stream>>>(adj, S1hT, S1lT, CP);
    // 5. H = relu(. + b1)
    k_combine_bias_relu<<<NN, 256, 0, stream>>>(CP, b1, H);
    // 6. S2ᵀ = (H @ W2)ᵀ
    k_hw2<<<NN / 4, 256, 0, stream>>>(H, W2, S2T);
    // 7. softmax(adj @ S2 + b2)
    k_final<<<NN / 8, 256, 0, stream>>>(adj, S2T, b2, out);
}

// Round 3
// 267.468 us; speedup vs baseline: 1.4713x; 1.2604x over previous
//
#include <hip/hip_runtime.h>
#include <hip/hip_fp16.h>
#include <math.h>

// Problem dims
#define NN   8192   // nodes / rows
#define KD   8192   // K of big GEMMs
#define HID  200
#define NP   224    // HID padded to 14*16
#define OUTC 5

// GEMM tiling
#define BM   128
#define BK   32
#define KS   8      // K-split chunks
#define KCH  (KD / KS)     // 1024
#define NT   (KCH / BK)    // 32 K-steps per block
#define LPAD 40     // halves per LDS row (32 + 8 pad); 80B stride = 5*16B -> aligned b128, 2-way banks (free)

typedef _Float16 f16;
typedef __attribute__((ext_vector_type(4))) _Float16 f16x4;
typedef __attribute__((ext_vector_type(8))) _Float16 f16x8;
typedef __attribute__((ext_vector_type(4))) float f32x4;

// ============ 1. W1 [8192][200] fp32 -> W1fT [224][8192] fp16 (zero-padded, transposed) ============
__global__ __launch_bounds__(256) void k_prep_w1(const float* __restrict__ W1,
                                                 f16* __restrict__ BfT) {
    __shared__ float tile[64][65];
    const int k0 = blockIdx.x * 64;
    const int n0 = blockIdx.y * 64;
    const int t = threadIdx.x;
    #pragma unroll
    for (int p = 0; p < 16; ++p) {
        int idx = t + p * 256;              // 0..4095
        int kk = idx >> 6, nn = idx & 63;
        int n = n0 + nn;
        float v = (n < HID) ? W1[(size_t)(k0 + kk) * HID + n] : 0.0f;
        tile[kk][nn] = v;
    }
    __syncthreads();
    #pragma unroll
    for (int p = 0; p < 16; ++p) {
        int idx = t + p * 256;
        int nn = idx >> 6, kk = idx & 63;
        int n = n0 + nn;
        if (n < NP) BfT[(size_t)n * KD + k0 + kk] = (f16)tile[kk][nn];
    }
}

// ============ 2. main GEMM: CP[ky] = A[:, kchunk] @ B[kchunk, :]  ============
// 2-product: A split on the fly (Ah + unscaled Al), B single fp16. Single fp32 accumulator.
// A fp32 [8192][8192], B fp16ᵀ [224][8192]. Grid (64, KS), 512 thr (8 waves 4x2), 2 blocks/CU.
__global__ __launch_bounds__(512, 4) void k_gemm(const float* __restrict__ A,
                                                 const f16* __restrict__ BfT,
                                                 f16* __restrict__ CP) {
    __shared__ __align__(16) f16 Ah[BM * LPAD];   // 10240 B
    __shared__ __align__(16) f16 Al[BM * LPAD];   // 10240 B
    __shared__ __align__(16) f16 Bf[NP * LPAD];   // 17920 B   (total 38400 B -> 2 blocks/CU)

    const int t = threadIdx.x;
    const int lane = t & 63;
    const int wave = t >> 6;
    const int wm = wave >> 1, wn = wave & 1;   // 4 wave-rows x 2 wave-cols
    const int l15 = lane & 15, g = lane >> 4;  // MFMA frag coords
    const int m0 = blockIdx.x * BM;
    const size_t kc0 = (size_t)blockIdx.y * KCH;

    // staging: A -> thread owns one 8-float chunk (row t>>2, chunk t&3)
    const int arow = t >> 2, aq = t & 3;
    // B -> 896 f16x8 units (row u>>2, chunk u&3); u0 = t, u1 = t+512 when t<384 (wave-uniform)
    const int br0 = t >> 2, bq0 = t & 3;
    const int u1 = t + 512;
    const int br1 = u1 >> 2, bq1 = u1 & 3;
    const bool hasB1 = (t < 384);

    const float* Aptr = A + (size_t)(m0 + arow) * KD + kc0 + (size_t)aq * 8;
    const f16* B0p = BfT + (size_t)br0 * KD + kc0 + (size_t)bq0 * 8;
    const f16* B1p = BfT + (size_t)br1 * KD + kc0 + (size_t)bq1 * 8;

    f32x4 acc[2][7];
    #pragma unroll
    for (int m = 0; m < 2; ++m)
        #pragma unroll
        for (int n = 0; n < 7; ++n) acc[m][n] = (f32x4){0.f, 0.f, 0.f, 0.f};

    // staged registers (tile in flight)
    float4 v0, v1;
    f16x8 gb0, gb1;

    auto LOAD = [&](int ks) {
        v0 = *(const float4*)(Aptr + ks);
        v1 = *(const float4*)(Aptr + ks + 4);
        gb0 = *(const f16x8*)(B0p + ks);
        if (hasB1) gb1 = *(const f16x8*)(B1p + ks);
    };
    auto STORE = [&]() {
        f16x8 hv, lv;
        float vv[8] = {v0.x, v0.y, v0.z, v0.w, v1.x, v1.y, v1.z, v1.w};
        #pragma unroll
        for (int j = 0; j < 8; ++j) {
            f16 h = (f16)vv[j];
            hv[j] = h;
            lv[j] = (f16)(vv[j] - (float)h);   // unscaled lo (may be subnormal -> fine)
        }
        *(f16x8*)&Ah[arow * LPAD + aq * 8] = hv;
        *(f16x8*)&Al[arow * LPAD + aq * 8] = lv;
        *(f16x8*)&Bf[br0 * LPAD + bq0 * 8] = gb0;
        if (hasB1) *(f16x8*)&Bf[br1 * LPAD + bq1 * 8] = gb1;
    };

    LOAD(0);
    for (int i = 0; i < NT; ++i) {
        __syncthreads();                    // prev compute's LDS reads done
        STORE();                            // tile i regs -> LDS
        __syncthreads();                    // writes visible
        if (i + 1 < NT) LOAD((i + 1) * BK); // next tile loads in flight over MFMA

        f16x8 a_h[2], a_l[2];
        #pragma unroll
        for (int m = 0; m < 2; ++m) {
            int r = wm * 32 + m * 16 + l15;
            a_h[m] = *(const f16x8*)&Ah[r * LPAD + g * 8];
            a_l[m] = *(const f16x8*)&Al[r * LPAD + g * 8];
        }
        __builtin_amdgcn_s_setprio(1);
        #pragma unroll
        for (int n = 0; n < 7; ++n) {
            int c = wn * 112 + n * 16 + l15;
            f16x8 b = *(const f16x8*)&Bf[c * LPAD + g * 8];
            #pragma unroll
            for (int m = 0; m < 2; ++m) {
                acc[m][n] = __builtin_amdgcn_mfma_f32_16x16x32_f16(a_l[m], b, acc[m][n], 0, 0, 0);
                acc[m][n] = __builtin_amdgcn_mfma_f32_16x16x32_f16(a_h[m], b, acc[m][n], 0, 0, 0);
            }
        }
        __builtin_amdgcn_s_setprio(0);
    }

    // ---- epilogue: partial C (fp16) ----
    f16* o = CP + (size_t)blockIdx.y * ((size_t)NN * NP);
    #pragma unroll
    for (int m = 0; m < 2; ++m) {
        #pragma unroll
        for (int n = 0; n < 7; ++n) {
            int rb = m0 + wm * 32 + m * 16 + g * 4;
            int c = wn * 112 + n * 16 + l15;
            #pragma unroll
            for (int r = 0; r < 4; ++r)
                o[(size_t)(rb + r) * NP + c] = (f16)acc[m][n][r];
        }
    }
}

// ============ 3. combine KS fp16 partials -> fp16, TRANSPOSED (feeds GEMM2's B) ============
__global__ __launch_bounds__(256) void k_combine_split(const f16* __restrict__ CP,
                                                       f16* __restrict__ SfT) {
    __shared__ float tile[64][65];
    const size_t SZ = (size_t)NN * NP;
    const int m0 = blockIdx.x * 64;
    const int n0 = blockIdx.y * 64;
    const int t = threadIdx.x;
    #pragma unroll
    for (int gq = 0; gq < 4; ++gq) {
        int idx4 = t + gq * 256;            // 0..1023, each covers 4 cols
        int mm = idx4 >> 4;                 // 0..63
        int nn4 = (idx4 & 15) * 4;          // 0..60
        int n = n0 + nn4;
        float s0 = 0.f, s1 = 0.f, s2 = 0.f, s3 = 0.f;
        if (n + 4 <= NP) {
            #pragma unroll
            for (int p = 0; p < KS; ++p) {
                f16x4 v = *(const f16x4*)(CP + (size_t)p * SZ + (size_t)(m0 + mm) * NP + n);
                s0 += (float)v[0]; s1 += (float)v[1]; s2 += (float)v[2]; s3 += (float)v[3];
            }
        }
        tile[mm][nn4 + 0] = s0; tile[mm][nn4 + 1] = s1;
        tile[mm][nn4 + 2] = s2; tile[mm][nn4 + 3] = s3;
    }
    __syncthreads();
    #pragma unroll
    for (int p = 0; p < 16; ++p) {
        int idx = t + p * 256;
        int nn = idx >> 6, mm = idx & 63;
        int n = n0 + nn;
        if (n < NP) SfT[(size_t)n * KD + m0 + mm] = (f16)tile[mm][nn];
    }
}

// ============ 4. combine + bias + relu -> H fp32 [8192][224] ============
__global__ __launch_bounds__(256) void k_combine_bias_relu(const f16* __restrict__ CP,
                                                           const float* __restrict__ b1,
                                                           float* __restrict__ H) {
    const size_t SZ = (size_t)NN * NP;
    const int row = blockIdx.x;
    const int t = threadIdx.x;
    if (t < NP) {
        size_t off = (size_t)row * NP + t;
        float s = 0.f;
        #pragma unroll
        for (int p = 0; p < KS; ++p) s += (float)CP[off + p * SZ];
        s += (t < HID) ? b1[t] : 0.0f;
        H[off] = fmaxf(s, 0.0f);
    }
}

// ============ 5. S2ᵀ[5][8192] = (H @ W2)ᵀ — one wave per row ============
__global__ __launch_bounds__(256) void k_hw2(const float* __restrict__ H,
                                             const float* __restrict__ W2,
                                             float* __restrict__ S2T) {
    const int t = threadIdx.x;
    const int wave = t >> 6, lane = t & 63;
    const int row = blockIdx.x * 4 + wave;
    float acc[OUTC] = {0.f, 0.f, 0.f, 0.f, 0.f};
    for (int j = lane; j < HID; j += 64) {
        float h = H[(size_t)row * NP + j];
        #pragma unroll
        for (int c = 0; c < OUTC; ++c) acc[c] += h * W2[j * OUTC + c];
    }
    #pragma unroll
    for (int c = 0; c < OUTC; ++c)
        #pragma unroll
        for (int off = 32; off; off >>= 1) acc[c] += __shfl_down(acc[c], off, 64);
    if (lane == 0) {
        #pragma unroll
        for (int c = 0; c < OUTC; ++c) S2T[(size_t)c * NN + row] = acc[c];
    }
}

// ============ 6. logits = adj @ S2 + b2 ; softmax -> out. 8 rows per block. ============
__global__ __launch_bounds__(256) void k_final(const float* __restrict__ adj,
                                               const float* __restrict__ S2T,
                                               const float* __restrict__ b2,
                                               float* __restrict__ out) {
    __shared__ float red[4][8][OUTC];
    const int t = threadIdx.x, wave = t >> 6, lane = t & 63;
    const int row0 = blockIdx.x * 8;
    float acc[8][OUTC];
    #pragma unroll
    for (int r = 0; r < 8; ++r)
        #pragma unroll
        for (int c = 0; c < OUTC; ++c) acc[r][c] = 0.f;

    for (int jj = 0; jj < 8; ++jj) {
        int kb = (t + jj * 256) * 4;
        float4 s2[OUTC];
        #pragma unroll
        for (int c = 0; c < OUTC; ++c) s2[c] = *(const float4*)(S2T + (size_t)c * NN + kb);
        #pragma unroll
        for (int r = 0; r < 8; ++r) {
            float4 a = *(const float4*)(adj + (size_t)(row0 + r) * KD + kb);
            #pragma unroll
            for (int c = 0; c < OUTC; ++c)
                acc[r][c] += a.x * s2[c].x + a.y * s2[c].y + a.z * s2[c].z + a.w * s2[c].w;
        }
    }
    #pragma unroll
    for (int r = 0; r < 8; ++r)
        #pragma unroll
        for (int c = 0; c < OUTC; ++c) {
            float v = acc[r][c];
            #pragma unroll
            for (int off = 32; off; off >>= 1) v += __shfl_down(v, off, 64);
            if (lane == 0) red[wave][r][c] = v;
        }
    __syncthreads();
    if (t < 8) {
        int r = t;
        float lg[OUTC];
        #pragma unroll
        for (int c = 0; c < OUTC; ++c)
            lg[c] = red[0][r][c] + red[1][r][c] + red[2][r][c] + red[3][r][c] + b2[c];
        float mx = lg[0];
        #pragma unroll
        for (int c = 1; c < OUTC; ++c) mx = fmaxf(mx, lg[c]);
        float e[OUTC], s = 0.f;
        #pragma unroll
        for (int c = 0; c < OUTC; ++c) { e[c] = expf(lg[c] - mx); s += e[c]; }
        float inv = 1.0f / s;
        #pragma unroll
        for (int c = 0; c < OUTC; ++c) out[(size_t)(row0 + r) * OUTC + c] = e[c] * inv;
    }
}

// ===================== launcher =====================
extern "C" void kernel_launch(void* const* d_in, const int* in_sizes, int n_in,
                              void* d_out, int out_size, void* d_ws, size_t ws_size,
                              hipStream_t stream) {
    const float* x   = (const float*)d_in[0];
    const float* adj = (const float*)d_in[1];
    const float* W1  = (const float*)d_in[2];
    const float* b1  = (const float*)d_in[3];
    const float* W2  = (const float*)d_in[4];
    const float* b2  = (const float*)d_in[5];
    float* out = (float*)d_out;

    char* ws = (char*)d_ws;
    const size_t SPLIT_BYTES = (size_t)NP * KD * sizeof(f16);   // 3,670,016
    f16*   W1fT = (f16*)(ws);
    f16*   S1fT = (f16*)(ws + SPLIT_BYTES);
    float* H    = (float*)(ws + 2 * SPLIT_BYTES);
    float* S2T  = (float*)(ws + 2 * SPLIT_BYTES + (size_t)NN * NP * sizeof(float));
    f16*   CPf  = (f16*)(ws + 2 * SPLIT_BYTES + (size_t)NN * NP * sizeof(float)
                            + (size_t)OUTC * NN * sizeof(float));   // KS * NN*NP fp16 = 29.4 MB

    // 1. W1 -> padded, transposed fp16
    k_prep_w1<<<dim3(KD / 64, (NP + 63) / 64), 256, 0, stream>>>(W1, W1fT);
    // 2. S1 = x @ W1 (K-split fp16 partials)
    k_gemm<<<dim3(NN / BM, KS), 512, 0, stream>>>(x, W1fT, CPf);
    // 3. reduce partials -> S1ᵀ fp16
    k_combine_split<<<dim3(NN / 64, (NP + 63) / 64), 256, 0, stream>>>(CPf, S1fT);
    // 4. adj @ S1 (K-split fp16 partials)
    k_gemm<<<dim3(NN / BM, KS), 512, 0, stream>>>(adj, S1fT, CPf);
    // 5. H = relu(. + b1)
    k_combine_bias_relu<<<NN, 256, 0, stream>>>(CPf, b1, H);
    // 6. S2ᵀ = (H @ W2)ᵀ
    k_hw2<<<NN / 4, 256, 0, stream>>>(H, W2, S2T);
    // 7. softmax(adj @ S2 + b2)
    k_final<<<NN / 8, 256, 0, stream>>>(adj, S2T, b2, out);
}